// Round 1
// baseline (484.223 us; speedup 1.0000x reference)
//
#include <hip/hip_runtime.h>
#include <stdint.h>
#include <math.h>

#define NAG 8192
#define NC  128          // Cp16 row stride: exactly the 128 msg features
#define NSPLIT 8         // K splits of 1024 (fp16 private partials, no atomics)
#define LDB2 136         // B LDS row stride in shorts (128 + 8 pad)

typedef __attribute__((ext_vector_type(8))) short short8;
typedef __attribute__((ext_vector_type(4))) float floatx4;

__device__ __forceinline__ float bf2f(unsigned short u) {
    union { uint32_t i; float f; } v; v.i = ((uint32_t)u) << 16; return v.f;
}
__device__ __forceinline__ unsigned short f2bf(float f) {
    union { float f; uint32_t i; } v; v.f = f;
    uint32_t x = v.i;
    return (unsigned short)((x + 0x7FFFu + ((x >> 16) & 1u)) >> 16);  // RNE
}
__device__ __forceinline__ unsigned short f2h(float f) {
    union { _Float16 h; unsigned short u; } v; v.h = (_Float16)f; return v.u;
}
__device__ __forceinline__ float h2f(unsigned short u) {
    union { _Float16 h; unsigned short u; } v; v.u = u; return (float)v.h;
}
// per-wave dtype self-detection (uniform ballot in every wave; no cross-block flag)
__device__ __forceinline__ bool detect_f32(const void* W1, int t) {
    const unsigned short* w = (const unsigned short*)W1;
    int l = t & 63, big = 0;
    #pragma unroll
    for (int j = 0; j < 8; ++j) {
        float v = bf2f(w[l * 8 + j]);
        if (!(fabsf(v) <= 1e6f)) big = 1;   // catches huge and NaN (fp32 mantissa noise)
    }
    return __ballot(big) != 0ull;
}

// ---------------- Kernel E: encoder h = tanh(obs@W1+b1); writes h_f32 + hT (bf16, transposed) ----
__global__ __launch_bounds__(256) void kE_encode(
    const void* __restrict__ obs,             // [8192][64]
    const void* __restrict__ W1,              // [64][128]
    const void* __restrict__ b1,              // [128]
    float* __restrict__ h_f32,                // [8192][128]
    unsigned short* __restrict__ hT)          // [128][8192] bf16
{
    __shared__ float obs_lds[32][68];
    __shared__ unsigned short ht_lds[128][33];
    const int t = threadIdx.x;
    const int abase = blockIdx.x * 32;
    const bool isf = detect_f32(W1, t);

    {   // stage obs tile 32x64
        int a = t >> 3, c0 = (t & 7) * 8;
        if (isf) {
            const float* p = (const float*)obs;
            #pragma unroll
            for (int j = 0; j < 8; ++j)
                obs_lds[a][c0 + j] = p[(size_t)(abase + a) * 64 + c0 + j];
        } else {
            const unsigned short* p = (const unsigned short*)obs;
            #pragma unroll
            for (int j = 0; j < 8; ++j)
                obs_lds[a][c0 + j] = bf2f(p[(size_t)(abase + a) * 64 + c0 + j]);
        }
    }
    __syncthreads();

    const int o = t & 127;
    const int half = t >> 7;          // wave-uniform
    float acc[16];
    if (isf) {
        const float* Wp = (const float*)W1;
        float bias = ((const float*)b1)[o];
        #pragma unroll
        for (int i = 0; i < 16; ++i) acc[i] = bias;
        for (int k0 = 0; k0 < 64; k0 += 8) {
            float w[8];
            #pragma unroll
            for (int j = 0; j < 8; ++j) w[j] = Wp[(k0 + j) * 128 + o];
            #pragma unroll
            for (int j = 0; j < 8; ++j)
                #pragma unroll
                for (int i = 0; i < 16; ++i)
                    acc[i] = fmaf(obs_lds[half * 16 + i][k0 + j], w[j], acc[i]);
        }
    } else {
        const unsigned short* Wp = (const unsigned short*)W1;
        float bias = bf2f(((const unsigned short*)b1)[o]);
        #pragma unroll
        for (int i = 0; i < 16; ++i) acc[i] = bias;
        for (int k0 = 0; k0 < 64; k0 += 8) {
            float w[8];
            #pragma unroll
            for (int j = 0; j < 8; ++j) w[j] = bf2f(Wp[(k0 + j) * 128 + o]);
            #pragma unroll
            for (int j = 0; j < 8; ++j)
                #pragma unroll
                for (int i = 0; i < 16; ++i)
                    acc[i] = fmaf(obs_lds[half * 16 + i][k0 + j], w[j], acc[i]);
        }
    }
    #pragma unroll
    for (int i = 0; i < 16; ++i) {
        float th = tanhf(acc[i]);
        int a = half * 16 + i;
        h_f32[(size_t)(abase + a) * 128 + o] = th;
        ht_lds[o][a] = f2bf(th);
    }
    __syncthreads();

    for (int p = 0; p < 16; ++p) {    // 128 feature rows
        int n = p * 8 + (t >> 5);
        int a = t & 31;
        hT[(size_t)n * NAG + abase + a] = ht_lds[n][a];
    }
}

// ---------------- Kernel G: FUSED adj-read + msg-GEMM + deg ----------------
// Single pass over the 268 MB int32 adj matrix: A-fragments fed directly from
// int32 {0,1} values (converted to bf16 in-register, bit-identical to the old
// bits path), deg accumulated as an exact integer side-sum of the same loads.
// Eliminates the separate bitpack pass (a full 268 MB read) + bits round-trip.
__global__ __launch_bounds__(256, 4) void kG_msggemm(
    const int* __restrict__ adj,              // [8192][8192] int32 {0,1}
    const unsigned short* __restrict__ hT,    // [128][8192] bf16
    unsigned short* __restrict__ Cp16,        // [NSPLIT][8192][128] fp16 partials
    int* __restrict__ degP)                   // [NSPLIT][8192] int partial degrees
{
    __shared__ __align__(16) unsigned short Blds[128 * LDB2];  // 34,816 B -> 4 blocks/CU
    const int t = threadIdx.x;
    const int mtile = blockIdx.x & 127;       // 128 M-tiles of 64 rows
    const int ks = blockIdx.x >> 7;           // 8 K-splits of 1024
    const int row0 = mtile * 64;
    const int kbeg = ks * 1024;

    const int wave = t >> 6, lane = t & 63;
    const int fm = lane & 15, quad = lane >> 4;

    floatx4 acc[8];
    #pragma unroll
    for (int i = 0; i < 8; ++i) acc[i] = (floatx4)0.f;

    const int arow = row0 + wave * 16 + fm;
    const int* ap = adj + (size_t)arow * NAG + kbeg + quad * 8;
    int dsum = 0;

    for (int ss = 0; ss < 8; ++ss) {          // 8 sub-slices of 128 k
        // A loads (HBM stream): no LDS dependency -> issue BEFORE the barrier,
        // overlapping the previous sub-slice's MFMA drain.
        int4 av[8];
        #pragma unroll
        for (int kw = 0; kw < 4; ++kw) {
            av[2 * kw]     = *reinterpret_cast<const int4*>(ap + ss * 128 + kw * 32);
            av[2 * kw + 1] = *reinterpret_cast<const int4*>(ap + ss * 128 + kw * 32 + 4);
        }
        if (ss) __syncthreads();              // prior compute done before LDS overwrite
        // stage B[128][128] (L2-hot hT): 2048 16B-chunks over 256 threads = 8 each
        #pragma unroll
        for (int i = 0; i < 8; ++i) {
            int idx = i * 256 + t;
            int row = idx >> 4, ch = idx & 15;
            uint4 v = *reinterpret_cast<const uint4*>(hT + (size_t)row * NAG + kbeg + ss * 128 + ch * 8);
            *reinterpret_cast<uint4*>(&Blds[row * LDB2 + ch * 8]) = v;
        }
        __syncthreads();                      // B resident (also drains av)
        #pragma unroll
        for (int kw = 0; kw < 4; ++kw) {      // 4 windows of 32 k
            const int* q = (const int*)&av[2 * kw];
            union { uint32_t u[4]; short8 s; } af;
            #pragma unroll
            for (int p = 0; p < 4; ++p) {
                uint32_t e0 = (q[2 * p]     != 0);
                uint32_t e1 = (q[2 * p + 1] != 0);
                dsum += (int)(e0 + e1);
                af.u[p] = (e0 | (e1 << 16)) * 0x3F80u;   // {0,1} pair -> bf16 pair, exact
            }
            #pragma unroll
            for (int j = 0; j < 8; ++j) {
                short8 bf = *reinterpret_cast<const short8*>(&Blds[(j * 16 + fm) * LDB2 + kw * 32 + quad * 8]);
                acc[j] = __builtin_amdgcn_mfma_f32_16x16x32_bf16(af.s, bf, acc[j], 0, 0, 0);
            }
        }
    }

    // deg partial: exact integer sum over this row's 1024-k slice.
    // quads hold disjoint k-subsets of the same row -> butterfly over lane^16, lane^32
    dsum += __shfl_xor(dsum, 16);
    dsum += __shfl_xor(dsum, 32);
    if (lane < 16) degP[ks * NAG + arow] = dsum;   // each (ks,row) written exactly once

    // epilogue: C/D layout col=lane&15, row=quad*4+reg; fp16 private partial per K-split
    unsigned short* out = Cp16 + (size_t)ks * (NAG * NC);
    #pragma unroll
    for (int j = 0; j < 8; ++j) {
        int col = j * 16 + fm;
        #pragma unroll
        for (int r = 0; r < 4; ++r) {
            int row = row0 + wave * 16 + quad * 4 + r;
            out[(size_t)row * NC + col] = f2h(acc[j][r]);
        }
    }
}

// ---------------- Kernel 3: deg = sum of degP partials; reduce Cp16; actor MLP ----------------
__global__ __launch_bounds__(256) void k3_actor(
    const float* __restrict__ h_f32,            // [8192][128]
    const unsigned short* __restrict__ Cp16,    // [NSPLIT][8192][128] fp16
    const int* __restrict__ degP,               // [NSPLIT][8192]
    const void* __restrict__ W1,                // for dtype self-detection
    const void* __restrict__ W2,                // [256][128]
    const void* __restrict__ b2,                // [128]
    const void* __restrict__ W3,                // [128][16]
    const void* __restrict__ b3,                // [16]
    void* __restrict__ out)                     // [8192][16]
{
    __shared__ float4 comb4[8][66];   // [agent][c-quad], c = 0..255
    __shared__ float hid[8][132];
    __shared__ int degs[8][9];
    __shared__ float inv_lds[8];
    const int t = threadIdx.x;
    const int abase = blockIdx.x * 8;
    const bool isf = detect_f32(W1, t);
    const size_t PS = (size_t)NAG * NC;

    if (t < 64) {   // gather 8 integer partials per agent
        int a = t >> 3, s = t & 7;
        degs[a][s] = degP[s * NAG + abase + a];
    }
    __syncthreads();
    if (t < 8) {
        int d = 0;
        #pragma unroll
        for (int s = 0; s < 8; ++s) d += degs[t][s];
        inv_lds[t] = 1.0f / fmaxf((float)d, 1.0f);
    }
    __syncthreads();

    // stage comb: 8 agents x 64 c-quads = 512 tasks over 256 threads
    #pragma unroll
    for (int jj = 0; jj < 2; ++jj) {
        int idx = jj * 256 + t;
        int a = idx >> 6, q = idx & 63;
        float4 v;
        if (q < 32) {   // h part
            v = *reinterpret_cast<const float4*>(h_f32 + (size_t)(abase + a) * 128 + q * 4);
        } else {        // msg part: sum NSPLIT fp16 partials, scale by 1/deg
            int f = (q - 32) * 4;
            float s0 = 0.f, s1 = 0.f, s2 = 0.f, s3 = 0.f;
            #pragma unroll
            for (int s = 0; s < NSPLIT; ++s) {
                ushort4 p = *reinterpret_cast<const ushort4*>(Cp16 + s * PS + (size_t)(abase + a) * NC + f);
                s0 += h2f(p.x); s1 += h2f(p.y); s2 += h2f(p.z); s3 += h2f(p.w);
            }
            float sc = inv_lds[a];
            v = make_float4(s0 * sc, s1 * sc, s2 * sc, s3 * sc);
        }
        comb4[a][q] = v;
    }
    __syncthreads();

    const int o = t & 127, half = t >> 7;   // 4 agents per half
    float acc[4];
    if (isf) {
        const float* Wp = (const float*)W2;
        float bias = ((const float*)b2)[o];
        #pragma unroll
        for (int i = 0; i < 4; ++i) acc[i] = bias;
        for (int cq = 0; cq < 64; ++cq) {
            float w0 = Wp[(cq * 4 + 0) * 128 + o];
            float w1 = Wp[(cq * 4 + 1) * 128 + o];
            float w2 = Wp[(cq * 4 + 2) * 128 + o];
            float w3 = Wp[(cq * 4 + 3) * 128 + o];
            #pragma unroll
            for (int i = 0; i < 4; ++i) {
                float4 v = comb4[half * 4 + i][cq];
                acc[i] = fmaf(v.x, w0, acc[i]);
                acc[i] = fmaf(v.y, w1, acc[i]);
                acc[i] = fmaf(v.z, w2, acc[i]);
                acc[i] = fmaf(v.w, w3, acc[i]);
            }
        }
    } else {
        const unsigned short* Wp = (const unsigned short*)W2;
        float bias = bf2f(((const unsigned short*)b2)[o]);
        #pragma unroll
        for (int i = 0; i < 4; ++i) acc[i] = bias;
        for (int cq = 0; cq < 64; ++cq) {
            float w0 = bf2f(Wp[(cq * 4 + 0) * 128 + o]);
            float w1 = bf2f(Wp[(cq * 4 + 1) * 128 + o]);
            float w2 = bf2f(Wp[(cq * 4 + 2) * 128 + o]);
            float w3 = bf2f(Wp[(cq * 4 + 3) * 128 + o]);
            #pragma unroll
            for (int i = 0; i < 4; ++i) {
                float4 v = comb4[half * 4 + i][cq];
                acc[i] = fmaf(v.x, w0, acc[i]);
                acc[i] = fmaf(v.y, w1, acc[i]);
                acc[i] = fmaf(v.z, w2, acc[i]);
                acc[i] = fmaf(v.w, w3, acc[i]);
            }
        }
    }
    #pragma unroll
    for (int i = 0; i < 4; ++i)
        hid[half * 4 + i][o] = tanhf(acc[i]);
    __syncthreads();

    if (t < 128) {   // 8 agents x 16 outputs
        const int q = t & 15, ar = t >> 4;
        float l;
        if (isf) {
            const float* Wp = (const float*)W3;
            l = ((const float*)b3)[q];
            #pragma unroll 4
            for (int oo = 0; oo < 128; ++oo)
                l = fmaf(hid[ar][oo], Wp[oo * 16 + q], l);
        } else {
            const unsigned short* Wp = (const unsigned short*)W3;
            l = bf2f(((const unsigned short*)b3)[q]);
            #pragma unroll 4
            for (int oo = 0; oo < 128; ++oo)
                l = fmaf(hid[ar][oo], bf2f(Wp[oo * 16 + q]), l);
        }
        size_t i0 = (size_t)(abase + ar) * 16 + q;
        if (isf) ((float*)out)[i0] = l;
        else     ((unsigned short*)out)[i0] = f2bf(l);
    }
}

extern "C" void kernel_launch(void* const* d_in, const int* in_sizes, int n_in,
                              void* d_out, int out_size, void* d_ws, size_t ws_size,
                              hipStream_t stream) {
    const void* obs = d_in[0];
    const int*  adj = (const int*)d_in[1];
    const void* W1  = d_in[2];
    const void* b1  = d_in[3];
    const void* W2  = d_in[4];
    const void* b2  = d_in[5];
    const void* W3  = d_in[6];
    const void* b3  = d_in[7];

    char* ws = (char*)d_ws;
    unsigned short* hT   = (unsigned short*)(ws);                    // 128*8192*2   =  2,097,152 B
    float*          h_f32= (float*)(ws + 2097152);                   // 8192*128*4   =  4,194,304 B
    unsigned short* Cp16 = (unsigned short*)(ws + 6291456);          // 8*8192*128*2 = 16,777,216 B
    int*            degP = (int*)(ws + 23068672);                    // 8*8192*4     =    262,144 B
                                                                     // total ~23.3 MB

    hipLaunchKernelGGL(kE_encode, dim3(256), dim3(256), 0, stream,
                       obs, W1, b1, h_f32, hT);
    hipLaunchKernelGGL(kG_msggemm, dim3(1024), dim3(256), 0, stream,
                       adj, hT, Cp16, degP);
    hipLaunchKernelGGL(k3_actor, dim3(1024), dim3(256), 0, stream,
                       h_f32, Cp16, degP, W1, W2, b2, W3, b3, d_out);
}

// Round 2
// 467.310 us; speedup vs baseline: 1.0362x; 1.0362x over previous
//
#include <hip/hip_runtime.h>
#include <stdint.h>
#include <math.h>

#define NAG 8192
#define NC  128          // Cp16 row stride: exactly the 128 msg features
#define NSPLIT 8         // K splits of 1024 (fp16 private partials, no atomics)
#define LDB2 136         // B LDS row stride in shorts (128 + 8 pad)

typedef __attribute__((ext_vector_type(8))) short short8;
typedef __attribute__((ext_vector_type(4))) float floatx4;

__device__ __forceinline__ float bf2f(unsigned short u) {
    union { uint32_t i; float f; } v; v.i = ((uint32_t)u) << 16; return v.f;
}
__device__ __forceinline__ unsigned short f2bf(float f) {
    union { float f; uint32_t i; } v; v.f = f;
    uint32_t x = v.i;
    return (unsigned short)((x + 0x7FFFu + ((x >> 16) & 1u)) >> 16);  // RNE
}
__device__ __forceinline__ unsigned short f2h(float f) {
    union { _Float16 h; unsigned short u; } v; v.h = (_Float16)f; return v.u;
}
__device__ __forceinline__ float h2f(unsigned short u) {
    union { _Float16 h; unsigned short u; } v; v.u = u; return (float)v.h;
}
// per-wave dtype self-detection (uniform ballot in every wave; no cross-block flag)
__device__ __forceinline__ bool detect_f32(const void* W1, int t) {
    const unsigned short* w = (const unsigned short*)W1;
    int l = t & 63, big = 0;
    #pragma unroll
    for (int j = 0; j < 8; ++j) {
        float v = bf2f(w[l * 8 + j]);
        if (!(fabsf(v) <= 1e6f)) big = 1;   // catches huge and NaN (fp32 mantissa noise)
    }
    return __ballot(big) != 0ull;
}

// ---------------- Kernel E: encoder h = tanh(obs@W1+b1); writes h_f32 + hT (bf16, transposed) ----
__global__ __launch_bounds__(256) void kE_encode(
    const void* __restrict__ obs,             // [8192][64]
    const void* __restrict__ W1,              // [64][128]
    const void* __restrict__ b1,              // [128]
    float* __restrict__ h_f32,                // [8192][128]
    unsigned short* __restrict__ hT)          // [128][8192] bf16
{
    __shared__ float obs_lds[32][68];
    __shared__ unsigned short ht_lds[128][33];
    const int t = threadIdx.x;
    const int abase = blockIdx.x * 32;
    const bool isf = detect_f32(W1, t);

    {   // stage obs tile 32x64
        int a = t >> 3, c0 = (t & 7) * 8;
        if (isf) {
            const float* p = (const float*)obs;
            #pragma unroll
            for (int j = 0; j < 8; ++j)
                obs_lds[a][c0 + j] = p[(size_t)(abase + a) * 64 + c0 + j];
        } else {
            const unsigned short* p = (const unsigned short*)obs;
            #pragma unroll
            for (int j = 0; j < 8; ++j)
                obs_lds[a][c0 + j] = bf2f(p[(size_t)(abase + a) * 64 + c0 + j]);
        }
    }
    __syncthreads();

    const int o = t & 127;
    const int half = t >> 7;          // wave-uniform
    float acc[16];
    if (isf) {
        const float* Wp = (const float*)W1;
        float bias = ((const float*)b1)[o];
        #pragma unroll
        for (int i = 0; i < 16; ++i) acc[i] = bias;
        for (int k0 = 0; k0 < 64; k0 += 8) {
            float w[8];
            #pragma unroll
            for (int j = 0; j < 8; ++j) w[j] = Wp[(k0 + j) * 128 + o];
            #pragma unroll
            for (int j = 0; j < 8; ++j)
                #pragma unroll
                for (int i = 0; i < 16; ++i)
                    acc[i] = fmaf(obs_lds[half * 16 + i][k0 + j], w[j], acc[i]);
        }
    } else {
        const unsigned short* Wp = (const unsigned short*)W1;
        float bias = bf2f(((const unsigned short*)b1)[o]);
        #pragma unroll
        for (int i = 0; i < 16; ++i) acc[i] = bias;
        for (int k0 = 0; k0 < 64; k0 += 8) {
            float w[8];
            #pragma unroll
            for (int j = 0; j < 8; ++j) w[j] = bf2f(Wp[(k0 + j) * 128 + o]);
            #pragma unroll
            for (int j = 0; j < 8; ++j)
                #pragma unroll
                for (int i = 0; i < 16; ++i)
                    acc[i] = fmaf(obs_lds[half * 16 + i][k0 + j], w[j], acc[i]);
        }
    }
    #pragma unroll
    for (int i = 0; i < 16; ++i) {
        float th = tanhf(acc[i]);
        int a = half * 16 + i;
        h_f32[(size_t)(abase + a) * 128 + o] = th;
        ht_lds[o][a] = f2bf(th);
    }
    __syncthreads();

    for (int p = 0; p < 16; ++p) {    // 128 feature rows
        int n = p * 8 + (t >> 5);
        int a = t & 31;
        hT[(size_t)n * NAG + abase + a] = ht_lds[n][a];
    }
}

// ---------------- Kernel G: FUSED adj-read + msg-GEMM + deg (in-register bitpack) ----------------
// R1 lesson: direct per-lane int4 adj reads scatter 16B requests across 16 rows
// (32KB stride) -> 991 GB/s. Fix: COALESCED ballot-bitpack. Each wave loads 64
// consecutive int32 of one row (256B/instruction), packs to a u64 via __ballot,
// parks it in 1KB LDS, then consumes 16B bit-fragments exactly like the proven
// bits-buffer path (identical bit layout: word w bit b = col w*32+b).
// deg comes free via popcount of the same fragments. Single 268MB adj pass.
__global__ __launch_bounds__(256, 4) void kG_msggemm(
    const int* __restrict__ adj,              // [8192][8192] int32 {0,1}
    const unsigned short* __restrict__ hT,    // [128][8192] bf16
    unsigned short* __restrict__ Cp16,        // [NSPLIT][8192][128] fp16 partials
    int* __restrict__ degP)                   // [NSPLIT][8192] int partial degrees
{
    __shared__ __align__(16) unsigned short Blds[128 * LDB2];       // 34,816 B
    __shared__ __align__(16) unsigned long long bitsLds[4][16][2];  // 1 KB (per-wave private)
    const int t = threadIdx.x;
    const int mtile = blockIdx.x & 127;       // 128 M-tiles of 64 rows
    const int ks = blockIdx.x >> 7;           // 8 K-splits of 1024
    const int row0 = mtile * 64;
    const int kbeg = ks * 1024;

    const int wave = t >> 6, lane = t & 63;
    const int fm = lane & 15, quad = lane >> 4;

    floatx4 acc[8];
    #pragma unroll
    for (int i = 0; i < 8; ++i) acc[i] = (floatx4)0.f;

    const int arow = row0 + wave * 16 + fm;
    // wave's 16-row block of adj, at this K-split's column window
    const int* wrows = adj + (size_t)(row0 + wave * 16) * NAG + kbeg;
    int dsum = 0;

    for (int ss = 0; ss < 8; ++ss) {          // 8 sub-slices of 128 k
        // (1) COALESCED adj loads: 32 x 256B per wave (16 rows x 2 half-rows).
        //     Issued before the barrier -> overlap previous sub-slice's MFMA drain.
        int va[32];
        #pragma unroll
        for (int i = 0; i < 32; ++i) {
            int r = i >> 1, hh = i & 1;
            va[i] = wrows[(size_t)r * NAG + ss * 128 + hh * 64 + lane];
        }
        if (ss) __syncthreads();              // prior compute done before LDS overwrite
        // (2) stage B[128][128] (L2-hot hT): 2048 16B-chunks over 256 threads = 8 each
        #pragma unroll
        for (int i = 0; i < 8; ++i) {
            int idx = i * 256 + t;
            int row = idx >> 4, ch = idx & 15;
            uint4 v = *reinterpret_cast<const uint4*>(hT + (size_t)row * NAG + kbeg + ss * 128 + ch * 8);
            *reinterpret_cast<uint4*>(&Blds[row * LDB2 + ch * 8]) = v;
        }
        // (3) pack bits: ballot per 64-col half-row; lane 0 parks u64 in LDS.
        //     bitsLds[wave] is wave-private: per-wave LDS ordering suffices, the
        //     block barrier below only protects Blds.
        #pragma unroll
        for (int i = 0; i < 32; ++i) {
            unsigned long long m = __ballot(va[i] != 0);
            if (lane == 0) bitsLds[wave][i >> 1][i & 1] = m;
        }
        __syncthreads();                      // B resident
        // (4) lane A-bits for this sub-slice: full 128-col bits of row fm (16B)
        int4 a0 = *reinterpret_cast<const int4*>(&bitsLds[wave][fm][0]);
        uint32_t aw[4] = {(uint32_t)a0.x, (uint32_t)a0.y, (uint32_t)a0.z, (uint32_t)a0.w};
        dsum += __popc(aw[0]) + __popc(aw[1]) + __popc(aw[2]) + __popc(aw[3]);
        #pragma unroll
        for (int kw = 0; kw < 4; ++kw) {      // 4 windows of 32 k
            uint32_t b = (aw[kw] >> (quad * 8)) & 0xFFu;
            union { uint32_t u[4]; short8 s; } af;
            #pragma unroll
            for (int p = 0; p < 4; ++p) {
                uint32_t bb = b >> (2 * p);
                af.u[p] = ((bb & 1u) | ((bb & 2u) << 15)) * 0x3F80u;   // {0,1}->bf16 pair, exact
            }
            #pragma unroll
            for (int j = 0; j < 8; ++j) {
                short8 bf = *reinterpret_cast<const short8*>(&Blds[(j * 16 + fm) * LDB2 + kw * 32 + quad * 8]);
                acc[j] = __builtin_amdgcn_mfma_f32_16x16x32_bf16(af.s, bf, acc[j], 0, 0, 0);
            }
        }
    }

    // deg partial: all 4 quads computed the identical full-row popcount -> write once
    if (quad == 0) degP[ks * NAG + arow] = dsum;

    // epilogue: C/D layout col=lane&15, row=quad*4+reg; fp16 private partial per K-split
    unsigned short* out = Cp16 + (size_t)ks * (NAG * NC);
    #pragma unroll
    for (int j = 0; j < 8; ++j) {
        int col = j * 16 + fm;
        #pragma unroll
        for (int r = 0; r < 4; ++r) {
            int row = row0 + wave * 16 + quad * 4 + r;
            out[(size_t)row * NC + col] = f2h(acc[j][r]);
        }
    }
}

// ---------------- Kernel 3: deg = sum of degP partials; reduce Cp16; actor MLP ----------------
__global__ __launch_bounds__(256) void k3_actor(
    const float* __restrict__ h_f32,            // [8192][128]
    const unsigned short* __restrict__ Cp16,    // [NSPLIT][8192][128] fp16
    const int* __restrict__ degP,               // [NSPLIT][8192]
    const void* __restrict__ W1,                // for dtype self-detection
    const void* __restrict__ W2,                // [256][128]
    const void* __restrict__ b2,                // [128]
    const void* __restrict__ W3,                // [128][16]
    const void* __restrict__ b3,                // [16]
    void* __restrict__ out)                     // [8192][16]
{
    __shared__ float4 comb4[8][66];   // [agent][c-quad], c = 0..255
    __shared__ float hid[8][132];
    __shared__ int degs[8][9];
    __shared__ float inv_lds[8];
    const int t = threadIdx.x;
    const int abase = blockIdx.x * 8;
    const bool isf = detect_f32(W1, t);
    const size_t PS = (size_t)NAG * NC;

    if (t < 64) {   // gather 8 integer partials per agent
        int a = t >> 3, s = t & 7;
        degs[a][s] = degP[s * NAG + abase + a];
    }
    __syncthreads();
    if (t < 8) {
        int d = 0;
        #pragma unroll
        for (int s = 0; s < 8; ++s) d += degs[t][s];
        inv_lds[t] = 1.0f / fmaxf((float)d, 1.0f);
    }
    __syncthreads();

    // stage comb: 8 agents x 64 c-quads = 512 tasks over 256 threads
    #pragma unroll
    for (int jj = 0; jj < 2; ++jj) {
        int idx = jj * 256 + t;
        int a = idx >> 6, q = idx & 63;
        float4 v;
        if (q < 32) {   // h part
            v = *reinterpret_cast<const float4*>(h_f32 + (size_t)(abase + a) * 128 + q * 4);
        } else {        // msg part: sum NSPLIT fp16 partials, scale by 1/deg
            int f = (q - 32) * 4;
            float s0 = 0.f, s1 = 0.f, s2 = 0.f, s3 = 0.f;
            #pragma unroll
            for (int s = 0; s < NSPLIT; ++s) {
                ushort4 p = *reinterpret_cast<const ushort4*>(Cp16 + s * PS + (size_t)(abase + a) * NC + f);
                s0 += h2f(p.x); s1 += h2f(p.y); s2 += h2f(p.z); s3 += h2f(p.w);
            }
            float sc = inv_lds[a];
            v = make_float4(s0 * sc, s1 * sc, s2 * sc, s3 * sc);
        }
        comb4[a][q] = v;
    }
    __syncthreads();

    const int o = t & 127, half = t >> 7;   // 4 agents per half
    float acc[4];
    if (isf) {
        const float* Wp = (const float*)W2;
        float bias = ((const float*)b2)[o];
        #pragma unroll
        for (int i = 0; i < 4; ++i) acc[i] = bias;
        for (int cq = 0; cq < 64; ++cq) {
            float w0 = Wp[(cq * 4 + 0) * 128 + o];
            float w1 = Wp[(cq * 4 + 1) * 128 + o];
            float w2 = Wp[(cq * 4 + 2) * 128 + o];
            float w3 = Wp[(cq * 4 + 3) * 128 + o];
            #pragma unroll
            for (int i = 0; i < 4; ++i) {
                float4 v = comb4[half * 4 + i][cq];
                acc[i] = fmaf(v.x, w0, acc[i]);
                acc[i] = fmaf(v.y, w1, acc[i]);
                acc[i] = fmaf(v.z, w2, acc[i]);
                acc[i] = fmaf(v.w, w3, acc[i]);
            }
        }
    } else {
        const unsigned short* Wp = (const unsigned short*)W2;
        float bias = bf2f(((const unsigned short*)b2)[o]);
        #pragma unroll
        for (int i = 0; i < 4; ++i) acc[i] = bias;
        for (int cq = 0; cq < 64; ++cq) {
            float w0 = bf2f(Wp[(cq * 4 + 0) * 128 + o]);
            float w1 = bf2f(Wp[(cq * 4 + 1) * 128 + o]);
            float w2 = bf2f(Wp[(cq * 4 + 2) * 128 + o]);
            float w3 = bf2f(Wp[(cq * 4 + 3) * 128 + o]);
            #pragma unroll
            for (int i = 0; i < 4; ++i) {
                float4 v = comb4[half * 4 + i][cq];
                acc[i] = fmaf(v.x, w0, acc[i]);
                acc[i] = fmaf(v.y, w1, acc[i]);
                acc[i] = fmaf(v.z, w2, acc[i]);
                acc[i] = fmaf(v.w, w3, acc[i]);
            }
        }
    }
    #pragma unroll
    for (int i = 0; i < 4; ++i)
        hid[half * 4 + i][o] = tanhf(acc[i]);
    __syncthreads();

    if (t < 128) {   // 8 agents x 16 outputs
        const int q = t & 15, ar = t >> 4;
        float l;
        if (isf) {
            const float* Wp = (const float*)W3;
            l = ((const float*)b3)[q];
            #pragma unroll 4
            for (int oo = 0; oo < 128; ++oo)
                l = fmaf(hid[ar][oo], Wp[oo * 16 + q], l);
        } else {
            const unsigned short* Wp = (const unsigned short*)W3;
            l = bf2f(((const unsigned short*)b3)[q]);
            #pragma unroll 4
            for (int oo = 0; oo < 128; ++oo)
                l = fmaf(hid[ar][oo], bf2f(Wp[oo * 16 + q]), l);
        }
        size_t i0 = (size_t)(abase + ar) * 16 + q;
        if (isf) ((float*)out)[i0] = l;
        else     ((unsigned short*)out)[i0] = f2bf(l);
    }
}

extern "C" void kernel_launch(void* const* d_in, const int* in_sizes, int n_in,
                              void* d_out, int out_size, void* d_ws, size_t ws_size,
                              hipStream_t stream) {
    const void* obs = d_in[0];
    const int*  adj = (const int*)d_in[1];
    const void* W1  = d_in[2];
    const void* b1  = d_in[3];
    const void* W2  = d_in[4];
    const void* b2  = d_in[5];
    const void* W3  = d_in[6];
    const void* b3  = d_in[7];

    char* ws = (char*)d_ws;
    unsigned short* hT   = (unsigned short*)(ws);                    // 128*8192*2   =  2,097,152 B
    float*          h_f32= (float*)(ws + 2097152);                   // 8192*128*4   =  4,194,304 B
    unsigned short* Cp16 = (unsigned short*)(ws + 6291456);          // 8*8192*128*2 = 16,777,216 B
    int*            degP = (int*)(ws + 23068672);                    // 8*8192*4     =    262,144 B
                                                                     // total ~23.3 MB

    hipLaunchKernelGGL(kE_encode, dim3(256), dim3(256), 0, stream,
                       obs, W1, b1, h_f32, hT);
    hipLaunchKernelGGL(kG_msggemm, dim3(1024), dim3(256), 0, stream,
                       adj, hT, Cp16, degP);
    hipLaunchKernelGGL(k3_actor, dim3(1024), dim3(256), 0, stream,
                       h_f32, Cp16, degP, W1, W2, b2, W3, b3, d_out);
}